// Round 3
// baseline (180.811 us; speedup 1.0000x reference)
//
#include <hip/hip_runtime.h>
#include <hip/hip_bf16.h>

// AdditiveAttention: B=8, Lq=128, Lk=512, Dq=Dk=H=Dv=256, fp32.
// out = softmax(mask(tanh(q[:,None]+k[None,:]) . wv)) @ V
// ws layout (floats): qproj[1024*256] | kproj[4096*256] | scores[1024*512]

#define SCALE_2LOG2E 2.885390081777927f   // 2*log2(e): e^(2x) = 2^(x*2log2e)
#define LOG2E        1.4426950408889634f
#define MASK_VALUE  -1000000.0f

__device__ __forceinline__ float fast_exp2(float x) {
#if __has_builtin(__builtin_amdgcn_exp2f)
    return __builtin_amdgcn_exp2f(x);
#else
    return exp2f(x);
#endif
}
__device__ __forceinline__ float fast_rcp(float x) {
#if __has_builtin(__builtin_amdgcn_rcpf)
    return __builtin_amdgcn_rcpf(x);
#else
    return __fdividef(1.0f, x);
#endif
}

// ---------------- fused projections ----------------------------------------
// grid 320 x 256 thr; 16 rows/block. Blocks 0-63 -> qproj, 64-319 -> kproj.
// X rows are wave-uniform loads (scalar path); W streamed coalesced per col.
__global__ __launch_bounds__(256) void proj_kernel(
    const float* __restrict__ queries, const float* __restrict__ keys,
    const float* __restrict__ Wq, const float* __restrict__ Wk,
    float* __restrict__ qproj, float* __restrict__ kproj)
{
    const int grow = blockIdx.x * 16;
    const float* X; const float* W; float* P; int row;
    if (grow < 1024) { X = queries; W = Wq; P = qproj; row = grow; }
    else             { X = keys;    W = Wk; P = kproj; row = grow - 1024; }
    const int col = threadIdx.x;

    float acc[16];
#pragma unroll
    for (int r = 0; r < 16; ++r) acc[r] = 0.f;

    for (int d4 = 0; d4 < 64; ++d4) {
        const int d = d4 * 4;
        const float w0 = W[(d + 0) * 256 + col];
        const float w1 = W[(d + 1) * 256 + col];
        const float w2 = W[(d + 2) * 256 + col];
        const float w3 = W[(d + 3) * 256 + col];
#pragma unroll
        for (int r = 0; r < 16; ++r) {
            const float4 xv = *(const float4*)(X + (row + r) * 256 + d); // uniform
            acc[r] += xv.x * w0 + xv.y * w1 + xv.z * w2 + xv.w * w3;
        }
    }
#pragma unroll
    for (int r = 0; r < 16; ++r)
        P[(row + r) * 256 + col] = acc[r] * SCALE_2LOG2E;
}

// ---------------- scores ----------------------------------------------------
// Block 256 thr = hg(8) x qb(4) x kb(8): 16 q-rows x 32 k-rows, H=256.
// Thread: 4q x 4k register tile, h-set = hg*32..+31 walked in 8 rotated quads.
// acc = sum_h w[h]*rcp(e^(2(q+k))+1); score = Wtot - 2*acc (tanh identity).
__global__ __launch_bounds__(256) void score_kernel(
    const float* __restrict__ qproj,   // [B*128][256] pre-scaled by 2log2e
    const float* __restrict__ kproj,   // [B*512][256] pre-scaled
    const float* __restrict__ wv,      // [256]
    const int*   __restrict__ valid_lens,
    float* __restrict__ scores)        // [B*128][512]
{
    __shared__ float qs[16][264];      // stride 264 (8-word pad)
    __shared__ float ks[32][264];

    const int b  = blockIdx.z;
    const int q0 = blockIdx.y * 16;
    const int k0 = blockIdx.x * 32;
    const int t  = threadIdx.x;
    const int hg = t & 7, qb = (t >> 3) & 3, kb = t >> 5;
    const int vlen = valid_lens[b];

    { // stage tiles (linear rows, padded stride)
        const float4* qsrc = (const float4*)(qproj + (b * 128 + q0) * 256);
        for (int i = t; i < 1024; i += 256)
            *(float4*)&qs[i >> 6][(i & 63) * 4] = qsrc[i];
        const float4* ksrc = (const float4*)(kproj + (b * 512 + k0) * 256);
        for (int i = t; i < 2048; i += 256)
            *(float4*)&ks[i >> 6][(i & 63) * 4] = ksrc[i];
    }

    // preload wv quads in rotated order; per-thread w-sum
    float4 wf[8]; float wsum = 0.f;
#pragma unroll
    for (int it = 0; it < 8; ++it) {
        const int m = (it + hg) & 7;
        wf[it] = *(const float4*)(wv + hg * 32 + m * 4);
        wsum += wf[it].x + wf[it].y + wf[it].z + wf[it].w;
    }
    __syncthreads();

    float acc[4][4];
#pragma unroll
    for (int i = 0; i < 4; ++i)
#pragma unroll
        for (int j = 0; j < 4; ++j) acc[i][j] = 0.f;

#pragma unroll
    for (int it = 0; it < 8; ++it) {
        const int m  = (it + hg) & 7;          // bank rotation across hg
        const int h0 = hg * 32 + m * 4;
        float4 qf[4], kf[4];
#pragma unroll
        for (int j = 0; j < 4; ++j) qf[j] = *(const float4*)&qs[qb * 4 + j][h0];
#pragma unroll
        for (int j = 0; j < 4; ++j) kf[j] = *(const float4*)&ks[kb * 4 + j][h0];
#pragma unroll
        for (int i = 0; i < 4; ++i)
#pragma unroll
            for (int j = 0; j < 4; ++j) {
                float a, e;
                a = qf[i].x + kf[j].x; e = fast_exp2(a);
                acc[i][j] += wf[it].x * fast_rcp(e + 1.f);
                a = qf[i].y + kf[j].y; e = fast_exp2(a);
                acc[i][j] += wf[it].y * fast_rcp(e + 1.f);
                a = qf[i].z + kf[j].z; e = fast_exp2(a);
                acc[i][j] += wf[it].z * fast_rcp(e + 1.f);
                a = qf[i].w + kf[j].w; e = fast_exp2(a);
                acc[i][j] += wf[it].w * fast_rcp(e + 1.f);
            }
    }

    // reduce over hg (lane bits 0-2); butterfly leaves full sum in all lanes
    float tot = wsum;
#pragma unroll
    for (int mask = 1; mask < 8; mask <<= 1) {
#pragma unroll
        for (int i = 0; i < 4; ++i)
#pragma unroll
            for (int j = 0; j < 4; ++j)
                acc[i][j] += __shfl_xor(acc[i][j], mask);
        tot += __shfl_xor(tot, mask);
    }

    if (hg == 0) {
#pragma unroll
        for (int i = 0; i < 4; ++i) {
            float* srow = scores + (b * 128 + q0 + qb * 4 + i) * 512 + k0 + kb * 4;
#pragma unroll
            for (int j = 0; j < 4; ++j) {
                const int kg = k0 + kb * 4 + j;
                srow[j] = (kg >= vlen) ? MASK_VALUE : (tot - 2.f * acc[i][j]);
            }
        }
    }
}

// ---------------- softmax + PV ----------------------------------------------
// Block 256 thr = 4 waves; 2 q-rows/block, each row split across 2 waves
// (k-halves). Attn stays in registers; broadcast via v_readlane; float4 V.
__global__ __launch_bounds__(256) void softmax_pv_kernel(
    const float* __restrict__ scores,  // [B*128][512]
    const float* __restrict__ values,  // [B][512][256]
    float* __restrict__ out)           // [B*128][256]
{
    __shared__ float pout[2][256];
    const int b = blockIdx.y, q0 = blockIdx.x * 2;
    const int t = threadIdx.x, w = t >> 6, lane = t & 63;
    const int rr = w >> 1, half = w & 1, row = q0 + rr;

    const float* srow = scores + (b * 128 + row) * 512;
    float sv[8];
#pragma unroll
    for (int j = 0; j < 8; ++j) sv[j] = srow[lane + 64 * j];

    float m = sv[0];
#pragma unroll
    for (int j = 1; j < 8; ++j) m = fmaxf(m, sv[j]);
#pragma unroll
    for (int o = 1; o < 64; o <<= 1) m = fmaxf(m, __shfl_xor(m, o));

    float sum = 0.f;
#pragma unroll
    for (int j = 0; j < 8; ++j) { sv[j] = fast_exp2((sv[j] - m) * LOG2E); sum += sv[j]; }
#pragma unroll
    for (int o = 1; o < 64; o <<= 1) sum += __shfl_xor(sum, o);
    const float rs = fast_rcp(sum);

    float pa[4];                      // this wave's k-half, literal indices
    if (half) { pa[0] = sv[4]; pa[1] = sv[5]; pa[2] = sv[6]; pa[3] = sv[7]; }
    else      { pa[0] = sv[0]; pa[1] = sv[1]; pa[2] = sv[2]; pa[3] = sv[3]; }
#pragma unroll
    for (int j = 0; j < 4; ++j) pa[j] *= rs;

    const float* V = values + (size_t)b * 512 * 256 + half * 256 * 256 + lane * 4;
    float4 acc = {0.f, 0.f, 0.f, 0.f};
#pragma unroll
    for (int j = 0; j < 4; ++j) {
#pragma unroll 8
        for (int l = 0; l < 64; ++l) {
            const int ai = __builtin_amdgcn_readlane(__float_as_int(pa[j]), l);
            const float a = __int_as_float(ai);        // SGPR broadcast
            const float4 v4 = *(const float4*)(V + (j * 64 + l) * 256);
            acc.x += a * v4.x; acc.y += a * v4.y;
            acc.z += a * v4.z; acc.w += a * v4.w;
        }
    }

    if (half) *(float4*)&pout[rr][lane * 4] = acc;
    __syncthreads();
    if (!half) {
        const float4 p = *(const float4*)&pout[rr][lane * 4];
        acc.x += p.x; acc.y += p.y; acc.z += p.z; acc.w += p.w;
        *(float4*)(out + (b * 128 + row) * 256 + lane * 4) = acc;
    }
}

extern "C" void kernel_launch(void* const* d_in, const int* in_sizes, int n_in,
                              void* d_out, int out_size, void* d_ws, size_t ws_size,
                              hipStream_t stream) {
    const float* queries = (const float*)d_in[0];
    const float* keys    = (const float*)d_in[1];
    const float* values  = (const float*)d_in[2];
    const int*   vlens   = (const int*)  d_in[3];
    const float* Wq      = (const float*)d_in[4];
    const float* Wk      = (const float*)d_in[5];
    const float* wv      = (const float*)d_in[6];
    float* out = (float*)d_out;

    float* qproj  = (float*)d_ws;                  // 1024*256
    float* kproj  = qproj + 1024 * 256;            // 4096*256
    float* scores = kproj + 4096 * 256;            // 1024*512

    proj_kernel<<<320, 256, 0, stream>>>(queries, keys, Wq, Wk, qproj, kproj);
    score_kernel<<<dim3(16, 8, 8), 256, 0, stream>>>(qproj, kproj, wv, vlens, scores);
    softmax_pv_kernel<<<dim3(64, 8), 256, 0, stream>>>(scores, values, out);
}

// Round 4
// 148.738 us; speedup vs baseline: 1.2156x; 1.2156x over previous
//
#include <hip/hip_runtime.h>
#include <hip/hip_bf16.h>

// AdditiveAttention: B=8, Lq=128, Lk=512, Dq=Dk=H=Dv=256, fp32.
// out = softmax(mask(tanh(q[:,None]+k[None,:]) . wv)) @ V
// ws layout (floats): qproj[1024*256] | kproj[4096*256] | scores[1024*512]
//
// vlen-adaptive: score tiles with k0 >= vlen are never computed/stored;
// softmax_pv substitutes -1e30 for k >= vlen and loops PV only to vlen.

#define SCALE_2LOG2E 2.885390081777927f   // 2*log2(e): e^(2x) = 2^(x*2log2e)
#define LOG2E        1.4426950408889634f
#define NEG_BIG     -1.0e30f

__device__ __forceinline__ float fast_exp2(float x) {
#if __has_builtin(__builtin_amdgcn_exp2f)
    return __builtin_amdgcn_exp2f(x);
#else
    return exp2f(x);
#endif
}
__device__ __forceinline__ float fast_rcp(float x) {
#if __has_builtin(__builtin_amdgcn_rcpf)
    return __builtin_amdgcn_rcpf(x);
#else
    return __fdividef(1.0f, x);
#endif
}

// ---------------- projections: tiled fp32 GEMM -------------------------------
// grid (4 n-tiles, 80 m-tiles), 256 thr. Tile 64x64, K=256 in 16 chunks of 16.
// m-tiles 0-15 -> qproj rows 0-1023; 16-79 -> kproj rows 0-4095.
// k-row tiles fully beyond valid_len are skipped (consumers never read them).
__global__ __launch_bounds__(256) void proj_kernel(
    const float* __restrict__ queries, const float* __restrict__ keys,
    const float* __restrict__ Wq, const float* __restrict__ Wk,
    const int* __restrict__ valid_lens,
    float* __restrict__ qproj, float* __restrict__ kproj)
{
    const int mt = blockIdx.y, nt = blockIdx.x;
    const float* X; const float* W; float* P; int row0;
    if (mt < 16) { X = queries; W = Wq; P = qproj; row0 = mt * 64; }
    else {
        const int kr = mt * 64 - 1024;           // 0..4095 global k-row
        const int b = kr >> 9, loc = kr & 511;
        if (loc >= valid_lens[b]) return;        // tile fully masked
        X = keys; W = Wk; P = kproj; row0 = kr;
    }
    const int t  = threadIdx.x;
    const int tx = t & 15, ty = t >> 4;          // output quad col/row
    const int ar = t >> 2, ac = t & 3;           // A stage: row, k-quad
    const int br = t >> 4, bc = t & 15;          // B stage: k-row, n-quad
    const int n0 = nt * 64;

    __shared__ float as[16][68];                 // as[k][m], pad 4
    __shared__ float bs[16][68];                 // bs[k][n], pad 4

    const float* Aptr = X + (size_t)(row0 + ar) * 256 + ac * 4;
    const float* Bptr = W + (size_t)br * 256 + n0 + bc * 4;

    float4 av = *(const float4*)Aptr;            // prefetch chunk 0
    float4 bv = *(const float4*)Bptr;

    float acc[4][4];
#pragma unroll
    for (int i = 0; i < 4; ++i)
#pragma unroll
        for (int j = 0; j < 4; ++j) acc[i][j] = 0.f;

    for (int ch = 0; ch < 16; ++ch) {
        __syncthreads();
        as[ac * 4 + 0][ar] = av.x;               // transpose A into LDS
        as[ac * 4 + 1][ar] = av.y;
        as[ac * 4 + 2][ar] = av.z;
        as[ac * 4 + 3][ar] = av.w;
        *(float4*)&bs[br][bc * 4] = bv;
        __syncthreads();
        if (ch < 15) {                           // prefetch next chunk
            av = *(const float4*)(Aptr + (ch + 1) * 16);
            bv = *(const float4*)(Bptr + (size_t)(ch + 1) * 16 * 256);
        }
#pragma unroll
        for (int kk = 0; kk < 16; ++kk) {
            const float4 af = *(const float4*)&as[kk][ty * 4];  // 4-addr bcast
            const float4 bf = *(const float4*)&bs[kk][tx * 4];  // 2-way
            acc[0][0] += af.x * bf.x; acc[0][1] += af.x * bf.y;
            acc[0][2] += af.x * bf.z; acc[0][3] += af.x * bf.w;
            acc[1][0] += af.y * bf.x; acc[1][1] += af.y * bf.y;
            acc[1][2] += af.y * bf.z; acc[1][3] += af.y * bf.w;
            acc[2][0] += af.z * bf.x; acc[2][1] += af.z * bf.y;
            acc[2][2] += af.z * bf.z; acc[2][3] += af.z * bf.w;
            acc[3][0] += af.w * bf.x; acc[3][1] += af.w * bf.y;
            acc[3][2] += af.w * bf.z; acc[3][3] += af.w * bf.w;
        }
    }
#pragma unroll
    for (int i = 0; i < 4; ++i) {
        float4 o;
        o.x = acc[i][0] * SCALE_2LOG2E; o.y = acc[i][1] * SCALE_2LOG2E;
        o.z = acc[i][2] * SCALE_2LOG2E; o.w = acc[i][3] * SCALE_2LOG2E;
        *(float4*)(P + (size_t)(row0 + ty * 4 + i) * 256 + n0 + tx * 4) = o;
    }
}

// ---------------- scores: thread per (q,k) pair ------------------------------
// grid (32 k-tiles, 8 q-tiles, 8 b), 256 thr = 16k x 16q. Tiles with
// k0 >= vlen skipped entirely. Per thread: scalar acc over all 256 h.
__global__ __launch_bounds__(256) void score_kernel(
    const float* __restrict__ qproj,   // [1024][256] pre-scaled by 2log2e
    const float* __restrict__ kproj,   // [4096][256] pre-scaled
    const float* __restrict__ wv,      // [256]
    const int*   __restrict__ valid_lens,
    float* __restrict__ scores)        // [1024][512]
{
    const int b  = blockIdx.z;
    const int vlen = valid_lens[b];
    const int k0 = blockIdx.x * 16;
    if (k0 >= vlen) return;                      // fully masked tile
    const int q0 = blockIdx.y * 16;
    const int t  = threadIdx.x;

    __shared__ float qs[16][260];                // stride 260: 2-way max
    __shared__ float ks[16][260];
    __shared__ float wl[256];

    { // stage q-tile, k-tile (16KB each), wv (1KB)
        const float4* qsrc = (const float4*)(qproj + (size_t)(b * 128 + q0) * 256);
        const float4* ksrc = (const float4*)(kproj + ((size_t)b * 512 + k0) * 256);
        for (int i = t; i < 1024; i += 256) {
            *(float4*)&qs[i >> 6][(i & 63) * 4] = qsrc[i];
            *(float4*)&ks[i >> 6][(i & 63) * 4] = ksrc[i];
        }
        if (t < 64) *(float4*)&wl[t * 4] = ((const float4*)wv)[t];
    }
    __syncthreads();

    const int tx = t & 15, ty = t >> 4;          // k-local, q-local
    float acc = 0.f;
#pragma unroll 8
    for (int h0 = 0; h0 < 256; h0 += 4) {
        const float4 qf = *(const float4*)&qs[ty][h0];
        const float4 kf = *(const float4*)&ks[tx][h0];
        const float4 wf = *(const float4*)&wl[h0];
        float a, r;
        a = qf.x + kf.x; r = fast_rcp(fast_exp2(a) + 1.f);
        acc += wf.x * (1.f - 2.f * r);
        a = qf.y + kf.y; r = fast_rcp(fast_exp2(a) + 1.f);
        acc += wf.y * (1.f - 2.f * r);
        a = qf.z + kf.z; r = fast_rcp(fast_exp2(a) + 1.f);
        acc += wf.z * (1.f - 2.f * r);
        a = qf.w + kf.w; r = fast_rcp(fast_exp2(a) + 1.f);
        acc += wf.w * (1.f - 2.f * r);
    }
    if (k0 + tx < vlen)
        scores[(size_t)(b * 128 + q0 + ty) * 512 + k0 + tx] = acc;
}

// ---------------- softmax + PV ----------------------------------------------
// grid (32, 8), 256 thr = 4 waves; wave = one q-row. Masked k handled by
// substituting -1e30 (exp -> 0); PV loops only k < vlen.
__global__ __launch_bounds__(256) void softmax_pv_kernel(
    const float* __restrict__ scores,  // [1024][512]
    const float* __restrict__ values,  // [8][512][256]
    const int*   __restrict__ valid_lens,
    float* __restrict__ out)           // [1024][256]
{
    __shared__ float attn[4][512];
    const int b = blockIdx.y, q0 = blockIdx.x * 4;
    const int t = threadIdx.x, w = t >> 6, lane = t & 63;
    const int vlen = valid_lens[b];
    const int row = q0 + w;

    const float* srow = scores + (size_t)(b * 128 + row) * 512;
    float sv[8];
#pragma unroll
    for (int j = 0; j < 8; ++j) {
        const int k = lane + 64 * j;
        sv[j] = (k < vlen) ? srow[k] : NEG_BIG;
    }

    float m = sv[0];
#pragma unroll
    for (int j = 1; j < 8; ++j) m = fmaxf(m, sv[j]);
#pragma unroll
    for (int o = 1; o < 64; o <<= 1) m = fmaxf(m, __shfl_xor(m, o));

    float sum = 0.f;
#pragma unroll
    for (int j = 0; j < 8; ++j) {
        sv[j] = fast_exp2((sv[j] - m) * LOG2E);  // masked -> exp2(-huge) = 0
        sum += sv[j];
    }
#pragma unroll
    for (int o = 1; o < 64; o <<= 1) sum += __shfl_xor(sum, o);
    const float rs = fast_rcp(sum);

#pragma unroll
    for (int j = 0; j < 8; ++j) attn[w][lane + 64 * j] = sv[j] * rs;
    // no __syncthreads: each wave reads only its own attn[w] row (same-wave
    // LDS RAW is ordered via compiler-inserted lgkmcnt waits)

    const float* V = values + (size_t)b * 512 * 256 + lane * 4;
    float4 acc = {0.f, 0.f, 0.f, 0.f};
#pragma unroll 4
    for (int k = 0; k < vlen; ++k) {
        const float a = attn[w][k];              // LDS broadcast
        const float4 v4 = *(const float4*)(V + (size_t)k * 256);
        acc.x += a * v4.x; acc.y += a * v4.y;
        acc.z += a * v4.z; acc.w += a * v4.w;
    }
    *(float4*)(out + (size_t)(b * 128 + row) * 256 + lane * 4) = acc;
}

extern "C" void kernel_launch(void* const* d_in, const int* in_sizes, int n_in,
                              void* d_out, int out_size, void* d_ws, size_t ws_size,
                              hipStream_t stream) {
    const float* queries = (const float*)d_in[0];
    const float* keys    = (const float*)d_in[1];
    const float* values  = (const float*)d_in[2];
    const int*   vlens   = (const int*)  d_in[3];
    const float* Wq      = (const float*)d_in[4];
    const float* Wk      = (const float*)d_in[5];
    const float* wv      = (const float*)d_in[6];
    float* out = (float*)d_out;

    float* qproj  = (float*)d_ws;                  // 1024*256
    float* kproj  = qproj + 1024 * 256;            // 4096*256
    float* scores = kproj + 4096 * 256;            // 1024*512

    proj_kernel<<<dim3(4, 80), 256, 0, stream>>>(queries, keys, Wq, Wk,
                                                 vlens, qproj, kproj);
    score_kernel<<<dim3(32, 8, 8), 256, 0, stream>>>(qproj, kproj, wv,
                                                     vlens, scores);
    softmax_pv_kernel<<<dim3(32, 8), 256, 0, stream>>>(scores, values,
                                                       vlens, out);
}

// Round 5
// 141.463 us; speedup vs baseline: 1.2781x; 1.0514x over previous
//
#include <hip/hip_runtime.h>
#include <hip/hip_bf16.h>

// AdditiveAttention: B=8, Lq=128, Lk=512, Dq=Dk=H=Dv=256, fp32.
// out = softmax(mask(tanh(q[:,None]+k[None,:]) . wv)) @ V
// ws layout (floats): qproj[1024*256] | kproj[4096*256] | scores[1024*512]
//
// vlen-adaptive: score tiles with k0 >= vlen are never computed/stored;
// softmax_pv substitutes -1e30 for k >= vlen and loops PV only to vl16.

#define SCALE_2LOG2E 2.885390081777927f   // 2*log2(e): e^(2x) = 2^(x*2log2e)
#define LOG2E        1.4426950408889634f
#define NEG_BIG     -1.0e30f

__device__ __forceinline__ float fast_exp2(float x) {
#if __has_builtin(__builtin_amdgcn_exp2f)
    return __builtin_amdgcn_exp2f(x);
#else
    return exp2f(x);
#endif
}
__device__ __forceinline__ float fast_rcp(float x) {
#if __has_builtin(__builtin_amdgcn_rcpf)
    return __builtin_amdgcn_rcpf(x);
#else
    return __fdividef(1.0f, x);
#endif
}

// ---------------- projections: tiled fp32 GEMM -------------------------------
// grid (4 n-tiles, 80 m-tiles), 256 thr. Tile 64x64, K=256 in 16 chunks of 16.
// m-tiles 0-15 -> qproj rows 0-1023; 16-79 -> kproj rows 0-4095.
// k-row tiles fully beyond valid_len are skipped (consumers never read them).
__global__ __launch_bounds__(256) void proj_kernel(
    const float* __restrict__ queries, const float* __restrict__ keys,
    const float* __restrict__ Wq, const float* __restrict__ Wk,
    const int* __restrict__ valid_lens,
    float* __restrict__ qproj, float* __restrict__ kproj)
{
    const int mt = blockIdx.y, nt = blockIdx.x;
    const float* X; const float* W; float* P; int row0;
    if (mt < 16) { X = queries; W = Wq; P = qproj; row0 = mt * 64; }
    else {
        const int kr = mt * 64 - 1024;           // 0..4095 global k-row
        const int b = kr >> 9, loc = kr & 511;
        if (loc >= valid_lens[b]) return;        // tile fully masked
        X = keys; W = Wk; P = kproj; row0 = kr;
    }
    const int t  = threadIdx.x;
    const int tx = t & 15, ty = t >> 4;          // output quad col/row
    const int ar = t >> 2, ac = t & 3;           // A stage: row, k-quad
    const int br = t >> 4, bc = t & 15;          // B stage: k-row, n-quad
    const int n0 = nt * 64;

    __shared__ float as[16][68];                 // as[k][m], pad 4
    __shared__ float bs[16][68];                 // bs[k][n], pad 4

    const float* Aptr = X + (size_t)(row0 + ar) * 256 + ac * 4;
    const float* Bptr = W + (size_t)br * 256 + n0 + bc * 4;

    float4 av = *(const float4*)Aptr;            // prefetch chunk 0
    float4 bv = *(const float4*)Bptr;

    float acc[4][4];
#pragma unroll
    for (int i = 0; i < 4; ++i)
#pragma unroll
        for (int j = 0; j < 4; ++j) acc[i][j] = 0.f;

    for (int ch = 0; ch < 16; ++ch) {
        __syncthreads();
        as[ac * 4 + 0][ar] = av.x;               // transpose A into LDS
        as[ac * 4 + 1][ar] = av.y;
        as[ac * 4 + 2][ar] = av.z;
        as[ac * 4 + 3][ar] = av.w;
        *(float4*)&bs[br][bc * 4] = bv;
        __syncthreads();
        if (ch < 15) {                           // prefetch next chunk
            av = *(const float4*)(Aptr + (ch + 1) * 16);
            bv = *(const float4*)(Bptr + (size_t)(ch + 1) * 16 * 256);
        }
#pragma unroll
        for (int kk = 0; kk < 16; ++kk) {
            const float4 af = *(const float4*)&as[kk][ty * 4];  // 4-addr bcast
            const float4 bf = *(const float4*)&bs[kk][tx * 4];  // 2-way
            acc[0][0] += af.x * bf.x; acc[0][1] += af.x * bf.y;
            acc[0][2] += af.x * bf.z; acc[0][3] += af.x * bf.w;
            acc[1][0] += af.y * bf.x; acc[1][1] += af.y * bf.y;
            acc[1][2] += af.y * bf.z; acc[1][3] += af.y * bf.w;
            acc[2][0] += af.z * bf.x; acc[2][1] += af.z * bf.y;
            acc[2][2] += af.z * bf.z; acc[2][3] += af.z * bf.w;
            acc[3][0] += af.w * bf.x; acc[3][1] += af.w * bf.y;
            acc[3][2] += af.w * bf.z; acc[3][3] += af.w * bf.w;
        }
    }
#pragma unroll
    for (int i = 0; i < 4; ++i) {
        float4 o;
        o.x = acc[i][0] * SCALE_2LOG2E; o.y = acc[i][1] * SCALE_2LOG2E;
        o.z = acc[i][2] * SCALE_2LOG2E; o.w = acc[i][3] * SCALE_2LOG2E;
        *(float4*)(P + (size_t)(row0 + ty * 4 + i) * 256 + n0 + tx * 4) = o;
    }
}

// ---------------- scores: thread per (q,k) pair ------------------------------
// grid (32 k-tiles, 8 q-tiles, 8 b), 256 thr = 16k x 16q. Tiles with
// k0 >= vlen skipped entirely. score = wsum - 2*sum_h w[h]*rcp(e^(2(q+k))+1).
__global__ __launch_bounds__(256) void score_kernel(
    const float* __restrict__ qproj,   // [1024][256] pre-scaled by 2log2e
    const float* __restrict__ kproj,   // [4096][256] pre-scaled
    const float* __restrict__ wv,      // [256]
    const int*   __restrict__ valid_lens,
    float* __restrict__ scores)        // [1024][512]
{
    const int b  = blockIdx.z;
    const int vlen = valid_lens[b];
    const int k0 = blockIdx.x * 16;
    if (k0 >= vlen) return;                      // fully masked tile
    const int q0 = blockIdx.y * 16;
    const int t  = threadIdx.x;

    __shared__ float qs[16][260];                // stride 260: 2-way max
    __shared__ float ks[16][260];
    __shared__ float wl[256];

    { // stage q-tile, k-tile (16KB each), wv (1KB)
        const float4* qsrc = (const float4*)(qproj + (size_t)(b * 128 + q0) * 256);
        const float4* ksrc = (const float4*)(kproj + ((size_t)b * 512 + k0) * 256);
        for (int i = t; i < 1024; i += 256) {
            *(float4*)&qs[i >> 6][(i & 63) * 4] = qsrc[i];
            *(float4*)&ks[i >> 6][(i & 63) * 4] = ksrc[i];
        }
        if (t < 64) *(float4*)&wl[t * 4] = ((const float4*)wv)[t];
    }
    __syncthreads();

    // wsum = sum of all 256 wv, identical in every lane (butterfly)
    float wsum;
    {
        const float4 wq = *(const float4*)&wl[(t & 63) * 4];
        wsum = wq.x + wq.y + wq.z + wq.w;
#pragma unroll
        for (int o = 1; o < 64; o <<= 1) wsum += __shfl_xor(wsum, o);
    }

    const int tx = t & 15, ty = t >> 4;          // k-local, q-local
    float acc = 0.f;
#pragma unroll 8
    for (int h0 = 0; h0 < 256; h0 += 4) {
        const float4 qf = *(const float4*)&qs[ty][h0];
        const float4 kf = *(const float4*)&ks[tx][h0];
        const float4 wf = *(const float4*)&wl[h0];
        acc += wf.x * fast_rcp(fast_exp2(qf.x + kf.x) + 1.f);
        acc += wf.y * fast_rcp(fast_exp2(qf.y + kf.y) + 1.f);
        acc += wf.z * fast_rcp(fast_exp2(qf.z + kf.z) + 1.f);
        acc += wf.w * fast_rcp(fast_exp2(qf.w + kf.w) + 1.f);
    }
    if (k0 + tx < vlen)
        scores[(size_t)(b * 128 + q0 + ty) * 512 + k0 + tx] = wsum - 2.f * acc;
}

// ---------------- softmax + PV ----------------------------------------------
// grid (64, 8), 256 thr = 4 waves = 2 q-rows x 2 k-halves. Each wave computes
// the full softmax reduction for its row, writes its k-half of attn, runs PV
// over its k-half (16-k unrolled windows, 16 V loads in flight), then halves
// combine via LDS. Masked k -> attn 0, PV bounded by vl16.
__global__ __launch_bounds__(256) void softmax_pv_kernel(
    const float* __restrict__ scores,  // [1024][512]
    const float* __restrict__ values,  // [8][512][256]
    const int*   __restrict__ valid_lens,
    float* __restrict__ out)           // [1024][256]
{
    __shared__ float attn[2][512];
    __shared__ float pout[2][256];
    const int b = blockIdx.y, q0 = blockIdx.x * 2;
    const int t = threadIdx.x, w = t >> 6, lane = t & 63;
    const int rr = w & 1, half = w >> 1, row = q0 + rr;
    const int vlen = valid_lens[b];

    const float* srow = scores + (size_t)(b * 128 + row) * 512;
    float sv[8];
#pragma unroll
    for (int j = 0; j < 8; ++j) {
        const int k = lane + 64 * j;
        sv[j] = (k < vlen) ? srow[k] : NEG_BIG;
    }

    float m = sv[0];
#pragma unroll
    for (int j = 1; j < 8; ++j) m = fmaxf(m, sv[j]);
#pragma unroll
    for (int o = 1; o < 64; o <<= 1) m = fmaxf(m, __shfl_xor(m, o));

    float sum = 0.f;
#pragma unroll
    for (int j = 0; j < 8; ++j) {
        sv[j] = fast_exp2((sv[j] - m) * LOG2E);  // masked -> 0
        sum += sv[j];
    }
#pragma unroll
    for (int o = 1; o < 64; o <<= 1) sum += __shfl_xor(sum, o);
    const float rs = fast_rcp(sum);

    // write only this wave's k-half of attn (j = half*4 .. half*4+3)
#pragma unroll
    for (int j = 0; j < 4; ++j) {
        const int jj = half * 4 + j;
        attn[rr][lane + 64 * jj] = sv[jj] * rs;
    }
    // PV reads exactly the entries this wave wrote -> same-wave LDS ordering,
    // no barrier needed before the PV loop.

    const int vl16 = (vlen + 15) & ~15;          // attn is 0 on [vlen, vl16)
    const int kbeg = half * 256;
    const int kend = min(vl16, kbeg + 256);
    const float* V = values + (size_t)b * 512 * 256 + lane * 4;

    float4 acc = {0.f, 0.f, 0.f, 0.f};
    for (int k0 = kbeg; k0 < kend; k0 += 16) {
#pragma unroll
        for (int g = 0; g < 4; ++g) {
            const int kk = k0 + g * 4;
            const float4 aq = *(const float4*)&attn[rr][kk];
            const float4 v0 = *(const float4*)(V + (size_t)(kk + 0) * 256);
            const float4 v1 = *(const float4*)(V + (size_t)(kk + 1) * 256);
            const float4 v2 = *(const float4*)(V + (size_t)(kk + 2) * 256);
            const float4 v3 = *(const float4*)(V + (size_t)(kk + 3) * 256);
            acc.x += aq.x * v0.x + aq.y * v1.x + aq.z * v2.x + aq.w * v3.x;
            acc.y += aq.x * v0.y + aq.y * v1.y + aq.z * v2.y + aq.w * v3.y;
            acc.z += aq.x * v0.z + aq.y * v1.z + aq.z * v2.z + aq.w * v3.z;
            acc.w += aq.x * v0.w + aq.y * v1.w + aq.z * v2.w + aq.w * v3.w;
        }
    }

    if (half) *(float4*)&pout[rr][lane * 4] = acc;
    __syncthreads();
    if (!half) {
        const float4 p = *(const float4*)&pout[rr][lane * 4];
        acc.x += p.x; acc.y += p.y; acc.z += p.z; acc.w += p.w;
        *(float4*)(out + (size_t)(b * 128 + row) * 256 + lane * 4) = acc;
    }
}

extern "C" void kernel_launch(void* const* d_in, const int* in_sizes, int n_in,
                              void* d_out, int out_size, void* d_ws, size_t ws_size,
                              hipStream_t stream) {
    const float* queries = (const float*)d_in[0];
    const float* keys    = (const float*)d_in[1];
    const float* values  = (const float*)d_in[2];
    const int*   vlens   = (const int*)  d_in[3];
    const float* Wq      = (const float*)d_in[4];
    const float* Wk      = (const float*)d_in[5];
    const float* wv      = (const float*)d_in[6];
    float* out = (float*)d_out;

    float* qproj  = (float*)d_ws;                  // 1024*256
    float* kproj  = qproj + 1024 * 256;            // 4096*256
    float* scores = kproj + 4096 * 256;            // 1024*512

    proj_kernel<<<dim3(4, 80), 256, 0, stream>>>(queries, keys, Wq, Wk,
                                                 vlens, qproj, kproj);
    score_kernel<<<dim3(32, 8, 8), 256, 0, stream>>>(qproj, kproj, wv,
                                                     vlens, scores);
    softmax_pv_kernel<<<dim3(64, 8), 256, 0, stream>>>(scores, values,
                                                       vlens, out);
}

// Round 6
// 136.567 us; speedup vs baseline: 1.3240x; 1.0359x over previous
//
#include <hip/hip_runtime.h>
#include <hip/hip_bf16.h>

// AdditiveAttention: B=8, Lq=128, Lk=512, Dq=Dk=H=Dv=256, fp32.
// out = softmax(mask(tanh(q[:,None]+k[None,:]) . wv)) @ V
// ws layout (floats): qproj[1024*256] | kproj[4096*256] | scores[1024*512]
//
// vlen-adaptive: score tiles with k0 >= vlen are never computed/stored;
// softmax_pv substitutes -1e30 for k >= vlen and loops PV only to vl16.

#define SCALE_2LOG2E 2.885390081777927f   // 2*log2(e): e^(2x) = 2^(x*2log2e)
#define LOG2E        1.4426950408889634f
#define NEG_BIG     -1.0e30f

__device__ __forceinline__ float fast_exp2(float x) {
#if __has_builtin(__builtin_amdgcn_exp2f)
    return __builtin_amdgcn_exp2f(x);
#else
    return exp2f(x);
#endif
}
__device__ __forceinline__ float fast_rcp(float x) {
#if __has_builtin(__builtin_amdgcn_rcpf)
    return __builtin_amdgcn_rcpf(x);
#else
    return __fdividef(1.0f, x);
#endif
}

// ---------------- projections: tiled fp32 GEMM -------------------------------
// grid (4 n-tiles, 80 m-tiles), 256 thr. Tile 64x64, K=256 in 16 chunks of 16.
// m-tiles 0-15 -> qproj rows 0-1023; 16-79 -> kproj rows 0-4095.
// k-row tiles fully beyond valid_len are skipped (consumers never read them).
__global__ __launch_bounds__(256) void proj_kernel(
    const float* __restrict__ queries, const float* __restrict__ keys,
    const float* __restrict__ Wq, const float* __restrict__ Wk,
    const int* __restrict__ valid_lens,
    float* __restrict__ qproj, float* __restrict__ kproj)
{
    const int mt = blockIdx.y, nt = blockIdx.x;
    const float* X; const float* W; float* P; int row0;
    if (mt < 16) { X = queries; W = Wq; P = qproj; row0 = mt * 64; }
    else {
        const int kr = mt * 64 - 1024;           // 0..4095 global k-row
        const int b = kr >> 9, loc = kr & 511;
        if (loc >= valid_lens[b]) return;        // tile fully masked
        X = keys; W = Wk; P = kproj; row0 = kr;
    }
    const int t  = threadIdx.x;
    const int tx = t & 15, ty = t >> 4;          // output quad col/row
    const int ar = t >> 2, ac = t & 3;           // A stage: row, k-quad
    const int br = t >> 4, bc = t & 15;          // B stage: k-row, n-quad
    const int n0 = nt * 64;

    __shared__ float as[16][68];                 // as[k][m], pad 4
    __shared__ float bs[16][68];                 // bs[k][n], pad 4

    const float* Aptr = X + (size_t)(row0 + ar) * 256 + ac * 4;
    const float* Bptr = W + (size_t)br * 256 + n0 + bc * 4;

    float4 av = *(const float4*)Aptr;            // prefetch chunk 0
    float4 bv = *(const float4*)Bptr;

    float acc[4][4];
#pragma unroll
    for (int i = 0; i < 4; ++i)
#pragma unroll
        for (int j = 0; j < 4; ++j) acc[i][j] = 0.f;

    for (int ch = 0; ch < 16; ++ch) {
        __syncthreads();
        as[ac * 4 + 0][ar] = av.x;               // transpose A into LDS
        as[ac * 4 + 1][ar] = av.y;
        as[ac * 4 + 2][ar] = av.z;
        as[ac * 4 + 3][ar] = av.w;
        *(float4*)&bs[br][bc * 4] = bv;
        __syncthreads();
        if (ch < 15) {                           // prefetch next chunk
            av = *(const float4*)(Aptr + (ch + 1) * 16);
            bv = *(const float4*)(Bptr + (size_t)(ch + 1) * 16 * 256);
        }
#pragma unroll
        for (int kk = 0; kk < 16; ++kk) {
            const float4 af = *(const float4*)&as[kk][ty * 4];  // 4-addr bcast
            const float4 bf = *(const float4*)&bs[kk][tx * 4];  // 2-way
            acc[0][0] += af.x * bf.x; acc[0][1] += af.x * bf.y;
            acc[0][2] += af.x * bf.z; acc[0][3] += af.x * bf.w;
            acc[1][0] += af.y * bf.x; acc[1][1] += af.y * bf.y;
            acc[1][2] += af.y * bf.z; acc[1][3] += af.y * bf.w;
            acc[2][0] += af.z * bf.x; acc[2][1] += af.z * bf.y;
            acc[2][2] += af.z * bf.z; acc[2][3] += af.z * bf.w;
            acc[3][0] += af.w * bf.x; acc[3][1] += af.w * bf.y;
            acc[3][2] += af.w * bf.z; acc[3][3] += af.w * bf.w;
        }
    }
#pragma unroll
    for (int i = 0; i < 4; ++i) {
        float4 o;
        o.x = acc[i][0] * SCALE_2LOG2E; o.y = acc[i][1] * SCALE_2LOG2E;
        o.z = acc[i][2] * SCALE_2LOG2E; o.w = acc[i][3] * SCALE_2LOG2E;
        *(float4*)(P + (size_t)(row0 + ty * 4 + i) * 256 + n0 + tx * 4) = o;
    }
}

// ---------------- scores: thread per (q,k) pair ------------------------------
// grid (32 k-tiles, 8 q-tiles, 8 b), 256 thr = 16k x 16q. Tiles with
// k0 >= vlen skipped entirely. score = wsum - 2*sum_h w[h]*rcp(e^(2(q+k))+1).
// Two independent accumulator chains decouple FMA latency from trans pipe.
__global__ __launch_bounds__(256) void score_kernel(
    const float* __restrict__ qproj,   // [1024][256] pre-scaled by 2log2e
    const float* __restrict__ kproj,   // [4096][256] pre-scaled
    const float* __restrict__ wv,      // [256]
    const int*   __restrict__ valid_lens,
    float* __restrict__ scores)        // [1024][512]
{
    const int b  = blockIdx.z;
    const int vlen = valid_lens[b];
    const int k0 = blockIdx.x * 16;
    if (k0 >= vlen) return;                      // fully masked tile
    const int q0 = blockIdx.y * 16;
    const int t  = threadIdx.x;

    __shared__ float qs[16][260];                // stride 260: 2-way max
    __shared__ float ks[16][260];
    __shared__ float wl[256];

    { // stage q-tile, k-tile (16KB each), wv (1KB)
        const float4* qsrc = (const float4*)(qproj + (size_t)(b * 128 + q0) * 256);
        const float4* ksrc = (const float4*)(kproj + ((size_t)b * 512 + k0) * 256);
        for (int i = t; i < 1024; i += 256) {
            *(float4*)&qs[i >> 6][(i & 63) * 4] = qsrc[i];
            *(float4*)&ks[i >> 6][(i & 63) * 4] = ksrc[i];
        }
        if (t < 64) *(float4*)&wl[t * 4] = ((const float4*)wv)[t];
    }
    __syncthreads();

    // wsum = sum of all 256 wv, identical in every lane (butterfly)
    float wsum;
    {
        const float4 wq = *(const float4*)&wl[(t & 63) * 4];
        wsum = wq.x + wq.y + wq.z + wq.w;
#pragma unroll
        for (int o = 1; o < 64; o <<= 1) wsum += __shfl_xor(wsum, o);
    }

    const int tx = t & 15, ty = t >> 4;          // k-local, q-local
    float acc0 = 0.f, acc1 = 0.f;
#pragma unroll 4
    for (int h0 = 0; h0 < 256; h0 += 8) {
        const float4 qa = *(const float4*)&qs[ty][h0];
        const float4 ka = *(const float4*)&ks[tx][h0];
        const float4 wa = *(const float4*)&wl[h0];
        const float4 qb = *(const float4*)&qs[ty][h0 + 4];
        const float4 kb = *(const float4*)&ks[tx][h0 + 4];
        const float4 wb = *(const float4*)&wl[h0 + 4];
        acc0 += wa.x * fast_rcp(fast_exp2(qa.x + ka.x) + 1.f);
        acc1 += wb.x * fast_rcp(fast_exp2(qb.x + kb.x) + 1.f);
        acc0 += wa.y * fast_rcp(fast_exp2(qa.y + ka.y) + 1.f);
        acc1 += wb.y * fast_rcp(fast_exp2(qb.y + kb.y) + 1.f);
        acc0 += wa.z * fast_rcp(fast_exp2(qa.z + ka.z) + 1.f);
        acc1 += wb.z * fast_rcp(fast_exp2(qb.z + kb.z) + 1.f);
        acc0 += wa.w * fast_rcp(fast_exp2(qa.w + ka.w) + 1.f);
        acc1 += wb.w * fast_rcp(fast_exp2(qb.w + kb.w) + 1.f);
    }
    if (k0 + tx < vlen)
        scores[(size_t)(b * 128 + q0 + ty) * 512 + k0 + tx] =
            wsum - 2.f * (acc0 + acc1);
}

// ---------------- softmax + PV ----------------------------------------------
// grid (64, 8), 256 thr = 4 waves = 2 q-rows x 2 k-halves. PV processes
// windows of 16 k with 16 NAMED float4 V loads issued before any use
// (forces 16 loads in flight; round-4 postmortem: VGPR=20 => serialized
// loads at ~200cy each). __launch_bounds__(256,2) gives regalloc room.
__global__ __launch_bounds__(256, 2) void softmax_pv_kernel(
    const float* __restrict__ scores,  // [1024][512]
    const float* __restrict__ values,  // [8][512][256]
    const int*   __restrict__ valid_lens,
    float* __restrict__ out)           // [1024][256]
{
    __shared__ float attn[2][512];
    __shared__ float pout[2][256];
    const int b = blockIdx.y, q0 = blockIdx.x * 2;
    const int t = threadIdx.x, w = t >> 6, lane = t & 63;
    const int rr = w & 1, half = w >> 1, row = q0 + rr;
    const int vlen = valid_lens[b];

    const float* srow = scores + (size_t)(b * 128 + row) * 512;
    float sv[8];
#pragma unroll
    for (int j = 0; j < 8; ++j) {
        const int k = lane + 64 * j;
        sv[j] = (k < vlen) ? srow[k] : NEG_BIG;
    }

    float m = sv[0];
#pragma unroll
    for (int j = 1; j < 8; ++j) m = fmaxf(m, sv[j]);
#pragma unroll
    for (int o = 1; o < 64; o <<= 1) m = fmaxf(m, __shfl_xor(m, o));

    float sum = 0.f;
#pragma unroll
    for (int j = 0; j < 8; ++j) {
        sv[j] = fast_exp2((sv[j] - m) * LOG2E);  // masked -> 0
        sum += sv[j];
    }
#pragma unroll
    for (int o = 1; o < 64; o <<= 1) sum += __shfl_xor(sum, o);
    const float rs = fast_rcp(sum);

    // write only this wave's k-half of attn (j = half*4 .. half*4+3)
#pragma unroll
    for (int j = 0; j < 4; ++j) {
        const int jj = half * 4 + j;
        attn[rr][lane + 64 * jj] = sv[jj] * rs;
    }
    // PV reads exactly the entries this wave wrote -> same-wave LDS ordering,
    // no barrier needed before the PV loop.

    const int vl16 = (vlen + 15) & ~15;          // attn is 0 on [vlen, vl16)
    const int kbeg = half * 256;
    const int kend = min(vl16, kbeg + 256);
    const float* V = values + (size_t)b * 512 * 256 + lane * 4;

    float4 acc = {0.f, 0.f, 0.f, 0.f};
    for (int k0 = kbeg; k0 < kend; k0 += 16) {
        const float* Vp = V + (size_t)k0 * 256;
        // 16 named loads, all issued before first use
        const float4 v0  = *(const float4*)(Vp +  0 * 256);
        const float4 v1  = *(const float4*)(Vp +  1 * 256);
        const float4 v2  = *(const float4*)(Vp +  2 * 256);
        const float4 v3  = *(const float4*)(Vp +  3 * 256);
        const float4 v4  = *(const float4*)(Vp +  4 * 256);
        const float4 v5  = *(const float4*)(Vp +  5 * 256);
        const float4 v6  = *(const float4*)(Vp +  6 * 256);
        const float4 v7  = *(const float4*)(Vp +  7 * 256);
        const float4 v8  = *(const float4*)(Vp +  8 * 256);
        const float4 v9  = *(const float4*)(Vp +  9 * 256);
        const float4 v10 = *(const float4*)(Vp + 10 * 256);
        const float4 v11 = *(const float4*)(Vp + 11 * 256);
        const float4 v12 = *(const float4*)(Vp + 12 * 256);
        const float4 v13 = *(const float4*)(Vp + 13 * 256);
        const float4 v14 = *(const float4*)(Vp + 14 * 256);
        const float4 v15 = *(const float4*)(Vp + 15 * 256);
        const float4 a0 = *(const float4*)&attn[rr][k0];
        const float4 a1 = *(const float4*)&attn[rr][k0 + 4];
        const float4 a2 = *(const float4*)&attn[rr][k0 + 8];
        const float4 a3 = *(const float4*)&attn[rr][k0 + 12];
        acc.x += a0.x*v0.x + a0.y*v1.x + a0.z*v2.x + a0.w*v3.x;
        acc.y += a0.x*v0.y + a0.y*v1.y + a0.z*v2.y + a0.w*v3.y;
        acc.z += a0.x*v0.z + a0.y*v1.z + a0.z*v2.z + a0.w*v3.z;
        acc.w += a0.x*v0.w + a0.y*v1.w + a0.z*v2.w + a0.w*v3.w;
        acc.x += a1.x*v4.x + a1.y*v5.x + a1.z*v6.x + a1.w*v7.x;
        acc.y += a1.x*v4.y + a1.y*v5.y + a1.z*v6.y + a1.w*v7.y;
        acc.z += a1.x*v4.z + a1.y*v5.z + a1.z*v6.z + a1.w*v7.z;
        acc.w += a1.x*v4.w + a1.y*v5.w + a1.z*v6.w + a1.w*v7.w;
        acc.x += a2.x*v8.x + a2.y*v9.x + a2.z*v10.x + a2.w*v11.x;
        acc.y += a2.x*v8.y + a2.y*v9.y + a2.z*v10.y + a2.w*v11.y;
        acc.z += a2.x*v8.z + a2.y*v9.z + a2.z*v10.z + a2.w*v11.z;
        acc.w += a2.x*v8.w + a2.y*v9.w + a2.z*v10.w + a2.w*v11.w;
        acc.x += a3.x*v12.x + a3.y*v13.x + a3.z*v14.x + a3.w*v15.x;
        acc.y += a3.x*v12.y + a3.y*v13.y + a3.z*v14.y + a3.w*v15.y;
        acc.z += a3.x*v12.z + a3.y*v13.z + a3.z*v14.z + a3.w*v15.z;
        acc.w += a3.x*v12.w + a3.y*v13.w + a3.z*v14.w + a3.w*v15.w;
    }

    if (half) *(float4*)&pout[rr][lane * 4] = acc;
    __syncthreads();
    if (!half) {
        const float4 p = *(const float4*)&pout[rr][lane * 4];
        acc.x += p.x; acc.y += p.y; acc.z += p.z; acc.w += p.w;
        *(float4*)(out + (size_t)(b * 128 + row) * 256 + lane * 4) = acc;
    }
}

extern "C" void kernel_launch(void* const* d_in, const int* in_sizes, int n_in,
                              void* d_out, int out_size, void* d_ws, size_t ws_size,
                              hipStream_t stream) {
    const float* queries = (const float*)d_in[0];
    const float* keys    = (const float*)d_in[1];
    const float* values  = (const float*)d_in[2];
    const int*   vlens   = (const int*)  d_in[3];
    const float* Wq      = (const float*)d_in[4];
    const float* Wk      = (const float*)d_in[5];
    const float* wv      = (const float*)d_in[6];
    float* out = (float*)d_out;

    float* qproj  = (float*)d_ws;                  // 1024*256
    float* kproj  = qproj + 1024 * 256;            // 4096*256
    float* scores = kproj + 4096 * 256;            // 1024*512

    proj_kernel<<<dim3(4, 80), 256, 0, stream>>>(queries, keys, Wq, Wk,
                                                 vlens, qproj, kproj);
    score_kernel<<<dim3(32, 8, 8), 256, 0, stream>>>(qproj, kproj, wv,
                                                     vlens, scores);
    softmax_pv_kernel<<<dim3(64, 8), 256, 0, stream>>>(scores, values,
                                                       vlens, out);
}

// Round 9
// 128.207 us; speedup vs baseline: 1.4103x; 1.0652x over previous
//
#include <hip/hip_runtime.h>
#include <hip/hip_bf16.h>

// AdditiveAttention: B=8, Lq=128, Lk=512, Dq=Dk=H=Dv=256, fp32.
// out = softmax(mask(tanh(q[:,None]+k[None,:]) . wv)) @ V
// ws layout (floats): qproj[1024*256] | kproj[4096*256] | scores[1024*512]

#define SCALE_2LOG2E 2.885390081777927f   // 2*log2(e): e^(2x) = 2^(x*2log2e)
#define LOG2E        1.4426950408889634f
#define NEG_BIG     -1.0e30f

__device__ __forceinline__ float fast_exp2(float x) {
#if __has_builtin(__builtin_amdgcn_exp2f)
    return __builtin_amdgcn_exp2f(x);
#else
    return exp2f(x);
#endif
}
__device__ __forceinline__ float fast_rcp(float x) {
#if __has_builtin(__builtin_amdgcn_rcpf)
    return __builtin_amdgcn_rcpf(x);
#else
    return __fdividef(1.0f, x);
#endif
}

// ---------------- projections: 64x64 tile, K-chunk 32, double-buffered -------
// grid (4 n, 80 m), 256 thr. ONE barrier per chunk (9 total, was 32).
// Global prefetch runs 2 chunks ahead; LDS buf A written while buf B computed.
__global__ __launch_bounds__(256) void proj_kernel(
    const float* __restrict__ queries, const float* __restrict__ keys,
    const float* __restrict__ Wq, const float* __restrict__ Wk,
    const int* __restrict__ valid_lens,
    float* __restrict__ qproj, float* __restrict__ kproj)
{
    const int mt = blockIdx.y, nt = blockIdx.x;
    const float* X; const float* W; float* P; int row0;
    if (mt < 16) { X = queries; W = Wq; P = qproj; row0 = mt * 64; }
    else {
        const int kr = mt * 64 - 1024;
        const int bb = kr >> 9, loc = kr & 511;
        if (loc >= valid_lens[bb]) return;       // tile fully masked
        X = keys; W = Wk; P = kproj; row0 = kr;
    }
    const int t  = threadIdx.x;
    const int tx = t & 15, ty = t >> 4;          // output quad col/row
    const int ar = t >> 2, ac = t & 3;           // A stage: row 0..63, k-quad
    const int br = t >> 3, bc = t & 7;           // B stage: k-row 0..31, n-quad
    const int n0 = nt * 64;

    __shared__ float as[2][32][68];              // as[buf][k][m]
    __shared__ float bs[2][32][68];              // bs[buf][k][n]

    const float* Aptr = X + (size_t)(row0 + ar) * 256 + ac * 4;
    const float* Bptr = W + (size_t)br * 256 + n0 + bc * 4;

    // prefetch chunk 0, write buf 0
    float4 av0 = *(const float4*)(Aptr);
    float4 av1 = *(const float4*)(Aptr + 16);
    float4 bv0 = *(const float4*)(Bptr);
    float4 bv1 = *(const float4*)(Bptr + 32);
    as[0][ac * 4 + 0][ar] = av0.x;  as[0][ac * 4 + 1][ar] = av0.y;
    as[0][ac * 4 + 2][ar] = av0.z;  as[0][ac * 4 + 3][ar] = av0.w;
    as[0][ac * 4 + 16][ar] = av1.x; as[0][ac * 4 + 17][ar] = av1.y;
    as[0][ac * 4 + 18][ar] = av1.z; as[0][ac * 4 + 19][ar] = av1.w;
    *(float4*)&bs[0][br][bc * 4]      = bv0;
    *(float4*)&bs[0][br][bc * 4 + 32] = bv1;
    // prefetch chunk 1 into regs
    av0 = *(const float4*)(Aptr + 32);
    av1 = *(const float4*)(Aptr + 48);
    bv0 = *(const float4*)(Bptr + 32 * 256);
    bv1 = *(const float4*)(Bptr + 32 * 256 + 32);
    __syncthreads();

    float acc[4][4];
#pragma unroll
    for (int i = 0; i < 4; ++i)
#pragma unroll
        for (int j = 0; j < 4; ++j) acc[i][j] = 0.f;

    for (int ch = 0; ch < 8; ++ch) {
        const int cur = ch & 1, nxt = cur ^ 1;
        if (ch < 7) {                            // write chunk ch+1 to other buf
            as[nxt][ac * 4 + 0][ar] = av0.x;  as[nxt][ac * 4 + 1][ar] = av0.y;
            as[nxt][ac * 4 + 2][ar] = av0.z;  as[nxt][ac * 4 + 3][ar] = av0.w;
            as[nxt][ac * 4 + 16][ar] = av1.x; as[nxt][ac * 4 + 17][ar] = av1.y;
            as[nxt][ac * 4 + 18][ar] = av1.z; as[nxt][ac * 4 + 19][ar] = av1.w;
            *(float4*)&bs[nxt][br][bc * 4]      = bv0;
            *(float4*)&bs[nxt][br][bc * 4 + 32] = bv1;
        }
        if (ch < 6) {                            // prefetch chunk ch+2
            av0 = *(const float4*)(Aptr + (ch + 2) * 32);
            av1 = *(const float4*)(Aptr + (ch + 2) * 32 + 16);
            bv0 = *(const float4*)(Bptr + (size_t)(ch + 2) * 32 * 256);
            bv1 = *(const float4*)(Bptr + (size_t)(ch + 2) * 32 * 256 + 32);
        }
#pragma unroll
        for (int kk = 0; kk < 32; ++kk) {
            const float4 af = *(const float4*)&as[cur][kk][ty * 4];
            const float4 bf = *(const float4*)&bs[cur][kk][tx * 4];
            acc[0][0] += af.x * bf.x; acc[0][1] += af.x * bf.y;
            acc[0][2] += af.x * bf.z; acc[0][3] += af.x * bf.w;
            acc[1][0] += af.y * bf.x; acc[1][1] += af.y * bf.y;
            acc[1][2] += af.y * bf.z; acc[1][3] += af.y * bf.w;
            acc[2][0] += af.z * bf.x; acc[2][1] += af.z * bf.y;
            acc[2][2] += af.z * bf.z; acc[2][3] += af.z * bf.w;
            acc[3][0] += af.w * bf.x; acc[3][1] += af.w * bf.y;
            acc[3][2] += af.w * bf.z; acc[3][3] += af.w * bf.w;
        }
        __syncthreads();
    }
#pragma unroll
    for (int i = 0; i < 4; ++i) {
        float4 o;
        o.x = acc[i][0] * SCALE_2LOG2E; o.y = acc[i][1] * SCALE_2LOG2E;
        o.z = acc[i][2] * SCALE_2LOG2E; o.w = acc[i][3] * SCALE_2LOG2E;
        *(float4*)(P + (size_t)(row0 + ty * 4 + i) * 256 + n0 + tx * 4) = o;
    }
}

// ---------------- scores: 2q x 2k x h-half per thread ------------------------
// grid (16 ktiles(32k), 8 qtiles(16q), 8 b), 256 thr = hg(2) x kp(16) x qp(8).
// Thread: rows {qp,qp+8} x {kp,kp+16}, h in [hg*128, +128). 5 LDS b128 reads
// per 16 tanh elems (was 12). Reduce over hg via 1 shfl_xor.
__global__ __launch_bounds__(256) void score_kernel(
    const float* __restrict__ qproj,   // [1024][256] pre-scaled by 2log2e
    const float* __restrict__ kproj,   // [4096][256] pre-scaled
    const float* __restrict__ wv,      // [256]
    const int*   __restrict__ valid_lens,
    float* __restrict__ scores)        // [1024][512]
{
    const int b  = blockIdx.z;
    const int vlen = valid_lens[b];
    const int k0 = blockIdx.x * 32;
    if (k0 >= vlen) return;
    const int q0 = blockIdx.y * 16;
    const int t  = threadIdx.x;

    __shared__ float qs[16][260];
    __shared__ float ks[32][260];
    __shared__ float wl[256];

    {
        const float4* qsrc = (const float4*)(qproj + (size_t)(b * 128 + q0) * 256);
        for (int i = t; i < 1024; i += 256)
            *(float4*)&qs[i >> 6][(i & 63) * 4] = qsrc[i];
        const float4* ksrc = (const float4*)(kproj + ((size_t)b * 512 + k0) * 256);
        for (int i = t; i < 2048; i += 256)
            *(float4*)&ks[i >> 6][(i & 63) * 4] = ksrc[i];
        if (t < 64) *(float4*)&wl[t * 4] = ((const float4*)wv)[t];
    }
    __syncthreads();

    float wsum;
    {
        const float4 wq = *(const float4*)&wl[(t & 63) * 4];
        wsum = wq.x + wq.y + wq.z + wq.w;
#pragma unroll
        for (int o = 1; o < 64; o <<= 1) wsum += __shfl_xor(wsum, o);
    }

    const int hg = t & 1, kp = (t >> 1) & 15, qp = t >> 5;
    const int hb = hg * 128;
    float a00 = 0.f, a01 = 0.f, a10 = 0.f, a11 = 0.f;   // [q][k]
#pragma unroll 8
    for (int hh = 0; hh < 32; ++hh) {
        const int h = hb + hh * 4;
        const float4 qa = *(const float4*)&qs[qp][h];
        const float4 qb = *(const float4*)&qs[qp + 8][h];
        const float4 ka = *(const float4*)&ks[kp][h];
        const float4 kb = *(const float4*)&ks[kp + 16][h];
        const float4 wf = *(const float4*)&wl[h];
        a00 += wf.x * fast_rcp(fast_exp2(qa.x + ka.x) + 1.f);
        a01 += wf.x * fast_rcp(fast_exp2(qa.x + kb.x) + 1.f);
        a10 += wf.x * fast_rcp(fast_exp2(qb.x + ka.x) + 1.f);
        a11 += wf.x * fast_rcp(fast_exp2(qb.x + kb.x) + 1.f);
        a00 += wf.y * fast_rcp(fast_exp2(qa.y + ka.y) + 1.f);
        a01 += wf.y * fast_rcp(fast_exp2(qa.y + kb.y) + 1.f);
        a10 += wf.y * fast_rcp(fast_exp2(qb.y + ka.y) + 1.f);
        a11 += wf.y * fast_rcp(fast_exp2(qb.y + kb.y) + 1.f);
        a00 += wf.z * fast_rcp(fast_exp2(qa.z + ka.z) + 1.f);
        a01 += wf.z * fast_rcp(fast_exp2(qa.z + kb.z) + 1.f);
        a10 += wf.z * fast_rcp(fast_exp2(qb.z + ka.z) + 1.f);
        a11 += wf.z * fast_rcp(fast_exp2(qb.z + kb.z) + 1.f);
        a00 += wf.w * fast_rcp(fast_exp2(qa.w + ka.w) + 1.f);
        a01 += wf.w * fast_rcp(fast_exp2(qa.w + kb.w) + 1.f);
        a10 += wf.w * fast_rcp(fast_exp2(qb.w + ka.w) + 1.f);
        a11 += wf.w * fast_rcp(fast_exp2(qb.w + kb.w) + 1.f);
    }
    a00 += __shfl_xor(a00, 1);
    a01 += __shfl_xor(a01, 1);
    a10 += __shfl_xor(a10, 1);
    a11 += __shfl_xor(a11, 1);

    if (hg == 0) {
        float* r0 = scores + (size_t)(b * 128 + q0 + qp) * 512;
        float* r1 = r0 + 8 * 512;
        const int c0 = k0 + kp, c1 = k0 + kp + 16;
        if (c0 < vlen) { r0[c0] = wsum - 2.f * a00; r1[c0] = wsum - 2.f * a10; }
        if (c1 < vlen) { r0[c1] = wsum - 2.f * a01; r1[c1] = wsum - 2.f * a11; }
    }
}

// ---------------- softmax + PV ----------------------------------------------
// grid (64, 8), 256 thr = 4 waves. Block = 2 q-rows; wave w = k-quarter
// [w*128, w*128+128) for BOTH rows (V amortized 2x). Each wave redundantly
// computes both rows' softmax in-reg (no cross-wave reduce/barrier), writes
// attn, PVs its quarter with 8 V-loads in flight, combines via LDS.
__global__ __launch_bounds__(256) void softmax_pv_kernel(
    const float* __restrict__ scores,  // [1024][512]
    const float* __restrict__ values,  // [8][512][256]
    const int*   __restrict__ valid_lens,
    float* __restrict__ out)           // [1024][256]
{
    __shared__ float attn[2][512];
    __shared__ float4 pout[4][2][64];
    const int b = blockIdx.y, q0 = blockIdx.x * 2;
    const int t = threadIdx.x, w = t >> 6, lane = t & 63;
    const int vlen = valid_lens[b];

    const float* s0 = scores + (size_t)(b * 128 + q0) * 512;
    const float* s1 = s0 + 512;
    float sv0[8], sv1[8];
#pragma unroll
    for (int j = 0; j < 8; ++j) {
        const int k = lane + 64 * j;
        const bool ok = k < vlen;
        sv0[j] = ok ? s0[k] : NEG_BIG;
        sv1[j] = ok ? s1[k] : NEG_BIG;
    }

    float m0 = sv0[0], m1 = sv1[0];
#pragma unroll
    for (int j = 1; j < 8; ++j) { m0 = fmaxf(m0, sv0[j]); m1 = fmaxf(m1, sv1[j]); }
#pragma unroll
    for (int o = 1; o < 64; o <<= 1) {
        m0 = fmaxf(m0, __shfl_xor(m0, o));
        m1 = fmaxf(m1, __shfl_xor(m1, o));
    }
    float su0 = 0.f, su1 = 0.f;
#pragma unroll
    for (int j = 0; j < 8; ++j) {
        sv0[j] = fast_exp2((sv0[j] - m0) * LOG2E); su0 += sv0[j];
        sv1[j] = fast_exp2((sv1[j] - m1) * LOG2E); su1 += sv1[j];
    }
#pragma unroll
    for (int o = 1; o < 64; o <<= 1) {
        su0 += __shfl_xor(su0, o);
        su1 += __shfl_xor(su1, o);
    }
    const float rs0 = fast_rcp(su0), rs1 = fast_rcp(su1);

    // every wave writes both full attn rows (redundant, identical values ->
    // benign; keeps sv indexing static and wave self-sufficient, no barrier)
#pragma unroll
    for (int j = 0; j < 8; ++j) {
        attn[0][lane + 64 * j] = sv0[j] * rs0;
        attn[1][lane + 64 * j] = sv1[j] * rs1;
    }

    const int kq = w * 128;
    const int kend = min(kq + 128, (vlen + 7) & ~7);   // attn==0 on [vlen,kend)
    const float* V = values + (size_t)b * 512 * 256 + lane * 4;
    float4 acc0 = {0.f, 0.f, 0.f, 0.f};
    float4 acc1 = {0.f, 0.f, 0.f, 0.f};

    for (int k = kq; k < kend; k += 8) {
        const float* Vp = V + (size_t)k * 256;
        const float4 v0 = *(const float4*)(Vp + 0 * 256);
        const float4 v1 = *(const float4*)(Vp + 1 * 256);
        const float4 v2 = *(const float4*)(Vp + 2 * 256);
        const float4 v3 = *(const float4*)(Vp + 3 * 256);
        const float4 v4 = *(const float4*)(Vp + 4 * 256);
        const float4 v5 = *(const float4*)(Vp + 5 * 256);
        const float4 v6 = *(const float4*)(Vp + 6 * 256);
        const float4 v7 = *(const float4*)(Vp + 7 * 256);
        const float4 a0 = *(const float4*)&attn[0][k];
        const float4 a4 = *(const float4*)&attn[0][k + 4];
        const float4 b0 = *(const float4*)&attn[1][k];
        const float4 b4 = *(const float4*)&attn[1][k + 4];
        acc0.x += a0.x*v0.x + a0.y*v1.x + a0.z*v2.x + a0.w*v3.x;
        acc0.y += a0.x*v0.y + a0.y*v1.y + a0.z*v2.y + a0.w*v3.y;
        acc0.z += a0.x*v0.z + a0.y*v1.z + a0.z*v2.z + a0.w*v3.z;
        acc0.w += a0.x*v0.w + a0.y*v1.w + a0.z*v2.w + a0.w*v3.w;
        acc1.x += b0.x*v0.x + b0.y*v1.x + b0.z*v2.x + b0.w*v3.x;
        acc1.y += b0.x*v0.y + b0.y*v1.y + b0.z*v2.y + b0.w*v3.y;
        acc1.z += b0.x*v0.z + b0.y*v1.z + b0.z*v2.z + b0.w*v3.z;
        acc1.w += b0.x*v0.w + b0.y*v1.w + b0.z*v2.w + b0.w*v3.w;
        acc0.x += a4.x*v4.x + a4.y*v5.x + a4.z*v6.x + a4.w*v7.x;
        acc0.y += a4.x*v4.y + a4.y*v5.y + a4.z*v6.y + a4.w*v7.y;
        acc0.z += a4.x*v4.z + a4.y*v5.z + a4.z*v6.z + a4.w*v7.z;
        acc0.w += a4.x*v4.w + a4.y*v5.w + a4.z*v6.w + a4.w*v7.w;
        acc1.x += b4.x*v4.x + b4.y*v5.x + b4.z*v6.x + b4.w*v7.x;
        acc1.y += b4.x*v4.y + b4.y*v5.y + b4.z*v6.y + b4.w*v7.y;
        acc1.z += b4.x*v4.z + b4.y*v5.z + b4.z*v6.z + b4.w*v7.z;
        acc1.w += b4.x*v4.w + b4.y*v5.w + b4.z*v6.w + b4.w*v7.w;
    }

    pout[w][0][lane] = acc0;
    pout[w][1][lane] = acc1;
    __syncthreads();
    if (t < 128) {
        const int r = t >> 6, lid = t & 63;
        float4 s = pout[0][r][lid];
        const float4 p1 = pout[1][r][lid], p2 = pout[2][r][lid], p3 = pout[3][r][lid];
        s.x += p1.x + p2.x + p3.x;
        s.y += p1.y + p2.y + p3.y;
        s.z += p1.z + p2.z + p3.z;
        s.w += p1.w + p2.w + p3.w;
        *(float4*)(out + (size_t)(b * 128 + q0 + r) * 256 + lid * 4) = s;
    }
}

extern "C" void kernel_launch(void* const* d_in, const int* in_sizes, int n_in,
                              void* d_out, int out_size, void* d_ws, size_t ws_size,
                              hipStream_t stream) {
    const float* queries = (const float*)d_in[0];
    const float* keys    = (const float*)d_in[1];
    const float* values  = (const float*)d_in[2];
    const int*   vlens   = (const int*)  d_in[3];
    const float* Wq      = (const float*)d_in[4];
    const float* Wk      = (const float*)d_in[5];
    const float* wv      = (const float*)d_in[6];
    float* out = (float*)d_out;

    float* qproj  = (float*)d_ws;                  // 1024*256
    float* kproj  = qproj + 1024 * 256;            // 4096*256
    float* scores = kproj + 4096 * 256;            // 1024*512

    proj_kernel<<<dim3(4, 80), 256, 0, stream>>>(queries, keys, Wq, Wk,
                                                 vlens, qproj, kproj);
    score_kernel<<<dim3(16, 8, 8), 256, 0, stream>>>(qproj, kproj, wv,
                                                     vlens, scores);
    softmax_pv_kernel<<<dim3(64, 8), 256, 0, stream>>>(scores, values,
                                                       vlens, out);
}